// Round 4
// baseline (1240.602 us; speedup 1.0000x reference)
//
#include <hip/hip_runtime.h>
#include <math.h>
#include <stdint.h>

#define FMW 50
#define P_IMG 2500
#define CIN 512
#define NANCH 22500
#define BATCH 16
#define PRE 512
#define POST 128
#define NCHUNK 44
#define NPAD (NCHUNK * 512)   // 22528
#define MB 96                 // block px tile
#define NTIL 27               // ceil(2500/96)
#define AWIN 200              // halo window: 52 + 96 + 52

typedef __attribute__((ext_vector_type(8))) short short8;
typedef __attribute__((ext_vector_type(16))) float f32x16;

union U4S8 { uint4 u; short8 s; };

__device__ __forceinline__ unsigned short f2bf(float x) {
    unsigned u = __float_as_uint(x);
    unsigned r = u + 0x7FFFu + ((u >> 16) & 1u);
    return (unsigned short)(r >> 16);
}
__device__ __forceinline__ float bf2f(unsigned short h) {
    return __uint_as_float(((unsigned)h) << 16);
}

// ---------------- K0: prepack w1 -> bf16 hi/lo MFMA-fragment order (coalesced) ----
// final layout (identical to V2/V3): (pos*32+c)*32768 + NT*2048 + s*1024 + lane*16
// frag content: lane l, byte-pair j: oc = NT*32 + (l&31), ci = c*16 + (l>>5)*8 + j
// grid: blockIdx = co_g(8) * 32 + c(32); block handles 64 oc x 16 ci x 9 pos.
__global__ __launch_bounds__(256)
void k_prepack(const float* __restrict__ w1, char* __restrict__ w1pack) {
    __shared__ char sm[36864];     // [pos(9)][s(2)][NT2(2)][lane(64)][16B]
    const int t = threadIdx.x;
    const int co_g = blockIdx.x >> 5;
    const int c = blockIdx.x & 31;
#pragma unroll
    for (int k = 0; k < 4; ++k) {
        int pi = k * 256 + t;              // 1024 (oc_l, ci_l) pairs
        int oc_l = pi >> 4, ci_l = pi & 15;
        int oc = co_g * 64 + oc_l;
        int ci = c * 16 + ci_l;
        int NT2 = oc_l >> 5;
        int lane = (oc_l & 31) + ((ci_l >> 3) << 5);
        int j = ci_l & 7;
        const float* src = w1 + ((size_t)oc * 512 + ci) * 9;
#pragma unroll
        for (int pos = 0; pos < 9; ++pos) {
            float x = src[pos];
            unsigned short h = f2bf(x);
            unsigned short lo = f2bf(x - bf2f(h));
            int b0 = ((pos * 2) * 2 + NT2) * 1024 + lane * 16 + j * 2;
            int b1 = ((pos * 2 + 1) * 2 + NT2) * 1024 + lane * 16 + j * 2;
            *(unsigned short*)(sm + b0) = h;
            *(unsigned short*)(sm + b1) = lo;
        }
    }
    __syncthreads();
    const int s = (t >> 6) & 1, NT2 = t >> 7, l = t & 63;
#pragma unroll
    for (int pos = 0; pos < 9; ++pos) {
        uint4 v = *(const uint4*)(sm + ((pos * 2 + s) * 2 + NT2) * 1024 + l * 16);
        *(uint4*)(w1pack + (size_t)(pos * 32 + c) * 32768
                  + ((co_g * 2 + NT2) * 2 + s) * 1024 + l * 16) = v;
    }
}

// ---------------- K1: MFMA conv — B in registers, barriers only per ci-chunk ------
// block = 256 thr = 4 waves (q = oc-quarter); block tile 96 px x 512 oc;
// wave tile 96 px x 128 oc (mt=3, nt=4, 12 f32x16 accs -> AGPR).
__global__ __launch_bounds__(256, 2)
void k_conv_mfma(const float* __restrict__ fm, const char* __restrict__ w1pack,
                 const float* __restrict__ b1, const float* __restrict__ w2,
                 const float* __restrict__ b2, const float* __restrict__ w3,
                 const float* __restrict__ b3,
                 float* __restrict__ off_ws, unsigned long long* __restrict__ keys) {
    // phase1: A-window hi [0,6400) + lo [6400,12800)   (px stride 32 B, 16 ci)
    // phase2: SH[128 oc][97 px] f32 = 49664 @0 | W[45][128] f32 = 23040 @49664
    __shared__ __align__(16) char smem[72704];

    const int t = threadIdx.x;
    const int l = t & 63;
    const int q = t >> 6;                  // wave = oc quarter 0..3
    const int img = blockIdx.x / NTIL;
    const int p0 = (blockIdx.x % NTIL) * MB;

    f32x16 acc[3][4];
#pragma unroll
    for (int mt = 0; mt < 3; ++mt)
#pragma unroll
        for (int nt = 0; nt < 4; ++nt)
#pragma unroll
            for (int g = 0; g < 16; ++g) acc[mt][nt][g] = 0.f;

    int xs[3];
#pragma unroll
    for (int mt = 0; mt < 3; ++mt) xs[mt] = (p0 + mt * 32 + (l & 31)) % FMW;

    const int arb = (52 + (l & 31)) * 32 + (l >> 5) * 16;
    const size_t img_base = (size_t)img * CIN * P_IMG;
    const int DPOS[9] = {-51, -50, -49, -1, 0, 1, 49, 50, 51};

    for (int c = 0; c < 32; ++c) {
        __syncthreads();                   // A-window free (reads of chunk c-1 done)
        // ---- stage A window: 200 px x 16 ci, hi/lo ----
#pragma unroll
        for (int k = 0; k < 4; ++k) {
            int flat = k * 256 + t;        // 800 items = 200 px x 4 ci-quads
            if (flat < 800) {
                int qq = flat & 3;
                int u = flat >> 2;
                int pw = p0 - 52 + u;
                bool ok = (pw >= 0) && (pw < P_IMG);
                float v[4];
#pragma unroll
                for (int kk = 0; kk < 4; ++kk)
                    v[kk] = ok ? fm[img_base + (size_t)(c * 16 + qq * 4 + kk) * P_IMG + pw] : 0.f;
                unsigned short h[4], lo[4];
#pragma unroll
                for (int kk = 0; kk < 4; ++kk) {
                    h[kk] = f2bf(v[kk]);
                    lo[kk] = f2bf(v[kk] - bf2f(h[kk]));
                }
                uint2 hu, lu;
                hu.x = h[0] | ((unsigned)h[1] << 16);  hu.y = h[2] | ((unsigned)h[3] << 16);
                lu.x = lo[0] | ((unsigned)lo[1] << 16); lu.y = lo[2] | ((unsigned)lo[3] << 16);
                *(uint2*)(smem + u * 32 + qq * 8) = hu;
                *(uint2*)(smem + 6400 + u * 32 + qq * 8) = lu;
            }
        }
        __syncthreads();

        for (int ky = 0; ky < 3; ++ky) {
            // ---- B for this ky row: 3 kx x 4 nt x {hi,lo} straight to registers ----
            uint4 bh[3][4], bl[3][4];
#pragma unroll
            for (int kx = 0; kx < 3; ++kx) {
                const char* bp = w1pack + (size_t)((ky * 3 + kx) * 32 + c) * 32768
                                 + (size_t)(q * 4) * 2048 + (size_t)l * 16;
#pragma unroll
                for (int nt = 0; nt < 4; ++nt) {
                    bh[kx][nt] = *(const uint4*)(bp + nt * 2048);
                    bl[kx][nt] = *(const uint4*)(bp + nt * 2048 + 1024);
                }
            }
#pragma unroll
            for (int kx = 0; kx < 3; ++kx) {
                const int pos = ky * 3 + kx;
                const int dpos = DPOS[pos];
                const int dx = kx - 1;
                U4S8 ah[3], al[3];
                const char* ap = smem + arb + dpos * 32;
#pragma unroll
                for (int mt = 0; mt < 3; ++mt) {
                    ah[mt].u = *(const uint4*)(ap + mt * 1024);
                    al[mt].u = *(const uint4*)(ap + 6400 + mt * 1024);
                    bool xok = (dx == 0) || (dx < 0 ? (xs[mt] > 0) : (xs[mt] < FMW - 1));
                    if (!xok) {
                        ah[mt].u.x = 0; ah[mt].u.y = 0; ah[mt].u.z = 0; ah[mt].u.w = 0;
                        al[mt].u.x = 0; al[mt].u.y = 0; al[mt].u.z = 0; al[mt].u.w = 0;
                    }
                }
#pragma unroll
                for (int nt = 0; nt < 4; ++nt) {
                    U4S8 vh, vl;
                    vh.u = bh[kx][nt]; vl.u = bl[kx][nt];
#pragma unroll
                    for (int mt = 0; mt < 3; ++mt) {
                        acc[mt][nt] = __builtin_amdgcn_mfma_f32_32x32x16_bf16(ah[mt].s, vh.s, acc[mt][nt], 0, 0, 0);
                        acc[mt][nt] = __builtin_amdgcn_mfma_f32_32x32x16_bf16(al[mt].s, vh.s, acc[mt][nt], 0, 0, 0);
                        acc[mt][nt] = __builtin_amdgcn_mfma_f32_32x32x16_bf16(ah[mt].s, vl.s, acc[mt][nt], 0, 0, 0);
                    }
                }
            }
        }
    }

    // ---------------- fused 1x1 epilogue (V3 order, 96-px SH) ----------------
    float* SH = (float*)smem;              // [128 oc][97 px]
    float* W  = (float*)(smem + 49664);    // [45][128]
    float b1v[4];
#pragma unroll
    for (int nt = 0; nt < 4; ++nt) b1v[nt] = b1[q * 128 + nt * 32 + (l & 31)];

    const int og = t / 96;                 // 0,1 active; 2 idle in dot
    const int px = t - og * 96;
    const int no = (og == 0) ? 23 : 22;
    float p45[23];
#pragma unroll
    for (int m = 0; m < 23; ++m) p45[m] = 0.f;

    for (int rr = 0; rr < 4; ++rr) {
        __syncthreads();
#pragma unroll
        for (int i = 0; i < 23; ++i) {
            int e = i * 256 + t;
            if (e < 5760) {
                int o = e >> 7, cl = e & 127;
                W[o * 128 + cl] = (o < 9) ? w2[o * 512 + rr * 128 + cl]
                                          : w3[(o - 9) * 512 + rr * 128 + cl];
            }
        }
        if (q == rr) {
#pragma unroll
            for (int nt = 0; nt < 4; ++nt) {
                int oc_l = nt * 32 + (l & 31);
#pragma unroll
                for (int mt = 0; mt < 3; ++mt)
#pragma unroll
                    for (int g = 0; g < 16; ++g) {
                        int row = (g & 3) + 8 * (g >> 2) + 4 * (l >> 5);
                        SH[oc_l * 97 + mt * 32 + row] =
                            fmaxf(acc[mt][nt][g] + b1v[nt], 0.f);
                    }
            }
        }
        __syncthreads();
        if (og < 2) {
            for (int cl = 0; cl < 128; ++cl) {
                float sv = SH[cl * 97 + px];
#pragma unroll
                for (int m = 0; m < 23; ++m)
                    if (m < no) p45[m] = fmaf(sv, W[(og * 23 + m) * 128 + cl], p45[m]);
            }
        }
    }

    const int pE = p0 + px;
    if (og < 2 && pE < P_IMG) {
        for (int m = 0; m < no; ++m) {
            int o = og * 23 + m;
            if (o < 9) {
                float z = p45[m] + b2[o];
                float s = (z >= 0.f) ? (1.f / (1.f + expf(-z)))
                                     : (expf(z) / (1.f + expf(z)));
                unsigned n = (unsigned)(pE * 9 + o);
                unsigned long long key =
                    ((unsigned long long)__float_as_uint(s) << 32) |
                    (unsigned long long)(0xFFFFFFFFu - n);
                keys[(size_t)img * NPAD + n] = key;
            } else {
                int cc = o - 9;
                off_ws[((size_t)img * P_IMG + pE) * 36 + cc] = p45[m] + b3[cc];
            }
        }
    }
}

// ---------------- K2: bitonic sort each 512-chunk descending (pad-guarded) --------
__global__ __launch_bounds__(256)
void k_sort_chunks(unsigned long long* __restrict__ keys) {
    __shared__ unsigned long long sk[512];
    const int t = threadIdx.x;
    const int img = blockIdx.x / NCHUNK;
    const int ch = blockIdx.x % NCHUNK;
    const size_t base = (size_t)img * NPAD + ch * 512;
    int a0 = ch * 512 + t, a1 = ch * 512 + t + 256;
    sk[t] = (a0 < NANCH) ? keys[base + t] : 0ull;
    sk[t + 256] = (a1 < NANCH) ? keys[base + t + 256] : 0ull;
    for (int k = 2; k <= 512; k <<= 1)
        for (int j = k >> 1; j > 0; j >>= 1) {
            __syncthreads();
            for (int i = t; i < 512; i += 256) {
                int lx = i ^ j;
                if (lx > i) {
                    unsigned long long a = sk[i], b = sk[lx];
                    bool desc = ((i & k) == 0);
                    if (desc ? (a < b) : (a > b)) { sk[i] = b; sk[lx] = a; }
                }
            }
        }
    __syncthreads();
    keys[base + t] = sk[t];
    keys[base + t + 256] = sk[t + 256];
}

// ---------------- K3: merge top-512, decode, NMS, top-128 (verified V1-V3) --------
__global__ __launch_bounds__(256)
void k_nms(const unsigned long long* __restrict__ keys,
           const float* __restrict__ off_ws, float* __restrict__ out) {
    __shared__ unsigned long long top[512];
    __shared__ unsigned long long chk[512];
    __shared__ float bx1[512], by1[512], bx2[512], by2[512], bar[512], bsc[512];
    __shared__ int keep[512];

    const int t = threadIdx.x;
    const int img = blockIdx.x;
    const size_t kbase = (size_t)img * NPAD;

    top[t] = keys[kbase + t];
    top[t + 256] = keys[kbase + t + 256];

    for (int c = 1; c < NCHUNK; ++c) {
        __syncthreads();
        chk[t] = keys[kbase + c * 512 + t];
        chk[t + 256] = keys[kbase + c * 512 + t + 256];
        __syncthreads();
        for (int i = t; i < 512; i += 256) {
            unsigned long long a = top[i], b = chk[511 - i];
            top[i] = (a > b) ? a : b;
        }
        for (int j = 256; j > 0; j >>= 1) {
            __syncthreads();
            int i = ((t & ~(j - 1)) << 1) | (t & (j - 1));
            unsigned long long a = top[i], b = top[i + j];
            if (a < b) { top[i] = b; top[i + j] = a; }
        }
    }
    __syncthreads();

    for (int i = t; i < 512; i += 256) {
        unsigned long long key = top[i];
        float s = __uint_as_float((unsigned)(key >> 32));
        unsigned id = 0xFFFFFFFFu - (unsigned)(key & 0xFFFFFFFFull);
        float x1 = 0.f, y1 = 0.f, x2 = 0.f, y2 = 0.f;
        bool valid = false;
        if (key != 0ull && id < (unsigned)NANCH) {
            int p = id / 9, a = id - p * 9;
            int gy = p / FMW, gx = p - gy * FMW;
            const double SS[3] = {32.0, 64.0, 128.0};
            const double RR[3] = {0.5, 1.0, 2.0};
            double sq = sqrt(RR[a % 3]);
            float wa32 = (float)(SS[a / 3] / sq);
            float ha32 = (float)(SS[a / 3] * sq);
            double cx = ((double)gx + 0.5) * 16.0;
            double cy = ((double)gy + 0.5) * 16.0;
            float ax1 = (float)(cx - (double)(wa32 * 0.5f));
            float ay1 = (float)(cy - (double)(ha32 * 0.5f));
            float ax2 = (float)(cx + (double)(wa32 * 0.5f));
            float ay2 = (float)(cy + (double)(ha32 * 0.5f));
            float aw = ax2 - ax1, ah2 = ay2 - ay1;
            float acx = ax1 + 0.5f * aw, acy = ay1 + 0.5f * ah2;
            const float4 off = *(const float4*)(off_ws + ((size_t)img * P_IMG + p) * 36 + a * 4);
            float px = acx + off.x * aw;
            float py = acy + off.y * ah2;
            float pw = aw * expf(off.z);
            float ph = ah2 * expf(off.w);
            x1 = fminf(fmaxf(px - 0.5f * pw, 0.f), 800.f);
            y1 = fminf(fmaxf(py - 0.5f * ph, 0.f), 800.f);
            x2 = fminf(fmaxf(px + 0.5f * pw, 0.f), 800.f);
            y2 = fminf(fmaxf(py + 0.5f * ph, 0.f), 800.f);
            float ww = x2 - x1, hh = y2 - y1;
            valid = (ww >= 1e-3f) && (hh >= 1e-3f) && (s >= 0.5f);
        }
        bx1[i] = x1; by1[i] = y1; bx2[i] = x2; by2[i] = y2;
        bar[i] = (x2 - x1) * (y2 - y1);
        bsc[i] = s;
        keep[i] = valid ? 1 : 0;
    }
    __syncthreads();

    for (int i = 0; i < PRE - 1; ++i) {
        __syncthreads();
        if (keep[i] == 0) continue;
        float xi1 = bx1[i], yi1 = by1[i], xi2 = bx2[i], yi2 = by2[i], ai = bar[i];
        for (int j = i + 1 + t; j < PRE; j += 256) {
            if (keep[j]) {
                float lx = fmaxf(xi1, bx1[j]);
                float ly = fmaxf(yi1, by1[j]);
                float rx = fminf(xi2, bx2[j]);
                float ry = fminf(yi2, by2[j]);
                float iw = fmaxf(rx - lx, 0.f);
                float ih = fmaxf(ry - ly, 0.f);
                float inter = iw * ih;
                float iou = inter / (ai + bar[j] - inter + 1e-9f);
                if (iou > 0.7f) keep[j] = 0;
            }
        }
    }
    __syncthreads();

    for (int i = t; i < 512; i += 256) {
        float m = keep[i] ? bsc[i] : -1.0f;
        unsigned u = __float_as_uint(m);
        u = (u & 0x80000000u) ? ~u : (u | 0x80000000u);
        chk[i] = ((unsigned long long)u << 32) | (unsigned long long)(511 - i);
    }
    for (int k = 2; k <= 512; k <<= 1)
        for (int j = k >> 1; j > 0; j >>= 1) {
            __syncthreads();
            for (int i = t; i < 512; i += 256) {
                int lx = i ^ j;
                if (lx > i) {
                    unsigned long long a = chk[i], b = chk[lx];
                    bool desc = ((i & k) == 0);
                    if (desc ? (a < b) : (a > b)) { chk[i] = b; chk[lx] = a; }
                }
            }
        }
    __syncthreads();

    if (t < POST) {
        unsigned long long key = chk[t];
        int slot = 511 - (int)(key & 0xFFFFFFFFull);
        float m = keep[slot] ? bsc[slot] : -1.0f;
        bool ok = (m >= 0.5f);
        float* ob = out + ((size_t)img * POST + t) * 4;
        ob[0] = ok ? bx1[slot] : 0.f;
        ob[1] = ok ? by1[slot] : 0.f;
        ob[2] = ok ? bx2[slot] : 0.f;
        ob[3] = ok ? by2[slot] : 0.f;
        out[(size_t)BATCH * POST * 4 + img * POST + t] = ok ? m : 0.f;
    }
}

// ---------------- launcher ----------------
extern "C" void kernel_launch(void* const* d_in, const int* in_sizes, int n_in,
                              void* d_out, int out_size, void* d_ws, size_t ws_size,
                              hipStream_t stream) {
    const float* fm = (const float*)d_in[0];
    const float* w1 = (const float*)d_in[1];
    const float* b1 = (const float*)d_in[2];
    const float* w2 = (const float*)d_in[3];
    const float* b2 = (const float*)d_in[4];
    const float* w3 = (const float*)d_in[5];
    const float* b3 = (const float*)d_in[6];
    float* out = (float*)d_out;

    char* ws = (char*)d_ws;
    // ws layout (18,087,936 B — identical to V2/V3 proven footprint):
    //   [0, 0x900000)           w1pack  (9,437,184 B)
    //   [0x900000, +5,760,000)  off_ws
    //   [0xE80000, +2,883,584)  keys
    char* w1pack = ws;
    float* off_ws = (float*)(ws + 0x900000);
    unsigned long long* keys = (unsigned long long*)(ws + 0xE80000);

    k_prepack<<<256, 256, 0, stream>>>(w1, w1pack);
    k_conv_mfma<<<BATCH * NTIL, 256, 0, stream>>>(fm, w1pack, b1, w2, b2, w3, b3, off_ws, keys);
    k_sort_chunks<<<BATCH * NCHUNK, 256, 0, stream>>>(keys);
    k_nms<<<BATCH, 256, 0, stream>>>(keys, off_ws, out);
}